// Round 7
// baseline (1048.436 us; speedup 1.0000x reference)
//
#include <hip/hip_runtime.h>
#include <hip/hip_bf16.h>

// ---------------- problem constants ----------------
#define FIN 165
#define HID 128
#define NPB 256        // nodes per bucket (bucket = dst >> 8)
#define MAXNB 784      // max bucket count (n=200000 -> 782)
#define CAP 4608       // bucket slot capacity (avg 4093, sigma~64 -> 8 sigma slack)
#define EPB 2048       // edges per scatter block
#define K32C1 6        // ceil(FIN/32)
#define K32C2 4        // HID/32

typedef __attribute__((ext_vector_type(8))) short short8;   // 8 bf16 (4 VGPRs)
typedef __attribute__((ext_vector_type(4))) float float4v;  // 4 fp32 acc

// round-to-nearest-even fp32 -> bf16 (returns low 16 bits)
__device__ inline unsigned bf16rne(float v) {
    unsigned u = __float_as_uint(v);
    return (u + 0x7fffu + ((u >> 16) & 1u)) >> 16;
}

// round-to-nearest-even fp32 -> bf16 split: v ~= hi + lo, residual ~ 2^-18 |v|
__device__ inline void bf16split(float v, short& h, short& l) {
    unsigned u = __float_as_uint(v);
    unsigned r = u + 0x7fffu + ((u >> 16) & 1u);
    h = (short)(r >> 16);
    float hf = __uint_as_float(((unsigned)(unsigned short)h) << 16);
    float lf = v - hf;                       // exact in fp32
    unsigned u2 = __float_as_uint(lf);
    unsigned r2 = u2 + 0x7fffu + ((u2 >> 16) & 1u);
    l = (short)(r2 >> 16);
}

// unpack packed bf16 pair -> two fp32
__device__ inline void bf2_unpack(unsigned u, float& f0, float& f1) {
    f0 = __uint_as_float(u << 16);
    f1 = __uint_as_float(u & 0xffff0000u);
}

// ---------------- W swizzle: fp32 [K x 128] -> bf16 hi/lo in MFMA B-frag order --------
__device__ inline void wswz_body(const float* W, short8* out, int K, int k32, int idx) {
    int tot = k32 * 8 * 64;
    if (idx >= tot) return;
    int lane = idx & 63;
    int ct = (idx >> 6) & 7;
    int ks = idx >> 9;
    int col = ct * 16 + (lane & 15);
    int kb = ks * 32 + (lane >> 4) * 8;
    short8 hi, lo;
#pragma unroll
    for (int j = 0; j < 8; ++j) {
        int k = kb + j;
        float v = (k < K) ? W[k * HID + col] : 0.f;
        short h, l;
        bf16split(v, h, l);
        hi[j] = h; lo[j] = l;
    }
    out[idx] = hi;
    out[tot + idx] = lo;
}

// R11: both weights in one tiny launch (12 + 8 blocks)
__global__ __launch_bounds__(256) void wswz_both(const float* __restrict__ W1p,
                                                 short8* __restrict__ o1,
                                                 const float* __restrict__ W2p,
                                                 short8* __restrict__ o2) {
    int bid = blockIdx.x;
    if (bid < 12) wswz_body(W1p, o1, FIN, K32C1, bid * 256 + threadIdx.x);
    else          wswz_body(W2p, o2, HID, K32C2, (bid - 12) * 256 + threadIdx.x);
}

// ---------------- MFMA GEMM body: H2raw[r, c-pair] = bf16x2((X@W)[r,c]) --------------
// R11: dinv REMOVED from the epilogue -> gemm1 is independent of the CSR build and
// can co-run with bucket_scatter in one fused launch. dinv[src] is applied per-edge
// in the aggregation (scalar s_load + fmac; SMEM pipe and VALU both have headroom).
__device__ void gemm_body(int bid, const float* __restrict__ X,
                          const short8* __restrict__ Wsw,
                          unsigned* __restrict__ H2, int K, int kfull, int k32) {
    int wave = threadIdx.x >> 6, lane = threadIdx.x & 63;
    int r0 = bid * 64 + wave * 16;
    int m = lane & 15, kph = lane >> 4;
    int row = r0 + m;
    const float* xrow = X + (size_t)row * K + kph * 8;
    const short8* Whi = Wsw;
    const short8* Wlo = Wsw + (size_t)k32 * 8 * 64;

    float4v acc[8];
#pragma unroll
    for (int ct = 0; ct < 8; ++ct) acc[ct] = (float4v){0.f, 0.f, 0.f, 0.f};

    for (int ks = 0; ks < kfull; ++ks) {
        float xv[8];
#pragma unroll
        for (int j = 0; j < 8; ++j) xv[j] = xrow[ks * 32 + j];
        short8 ah, al;
#pragma unroll
        for (int j = 0; j < 8; ++j) {
            short h, l; bf16split(xv[j], h, l);
            ah[j] = h; al[j] = l;
        }
#pragma unroll
        for (int ct = 0; ct < 8; ++ct) {
            short8 bh = Whi[(ks * 8 + ct) * 64 + lane];
            short8 bl = Wlo[(ks * 8 + ct) * 64 + lane];
            acc[ct] = __builtin_amdgcn_mfma_f32_16x16x32_bf16(ah, bh, acc[ct], 0, 0, 0);
            acc[ct] = __builtin_amdgcn_mfma_f32_16x16x32_bf16(al, bh, acc[ct], 0, 0, 0);
            acc[ct] = __builtin_amdgcn_mfma_f32_16x16x32_bf16(ah, bl, acc[ct], 0, 0, 0);
        }
    }
    if (kfull < k32) {                       // K-tail (layer 1: k = 160..164)
        int ks = kfull;
        int kb = ks * 32 + kph * 8;
        float xv[8];
#pragma unroll
        for (int j = 0; j < 8; ++j) xv[j] = (kb + j < K) ? xrow[ks * 32 + j] : 0.f;
        short8 ah, al;
#pragma unroll
        for (int j = 0; j < 8; ++j) {
            short h, l; bf16split(xv[j], h, l);
            ah[j] = h; al[j] = l;
        }
#pragma unroll
        for (int ct = 0; ct < 8; ++ct) {
            short8 bh = Whi[(ks * 8 + ct) * 64 + lane];
            short8 bl = Wlo[(ks * 8 + ct) * 64 + lane];
            acc[ct] = __builtin_amdgcn_mfma_f32_16x16x32_bf16(ah, bh, acc[ct], 0, 0, 0);
            acc[ct] = __builtin_amdgcn_mfma_f32_16x16x32_bf16(al, bh, acc[ct], 0, 0, 0);
            acc[ct] = __builtin_amdgcn_mfma_f32_16x16x32_bf16(ah, bl, acc[ct], 0, 0, 0);
        }
    }
    // epilogue: C/D layout col=lane&15, row=(lane>>4)*4+reg  [m89-verified]
    int ccol = lane & 15, crow = (lane >> 4) * 4;
    bool evenl = (ccol & 1) == 0;
#pragma unroll
    for (int r = 0; r < 4; ++r) {
        int gr = r0 + crow + r;
#pragma unroll
        for (int ct = 0; ct < 8; ++ct) {
            float v = acc[ct][r];
            float p = __shfl_xor(v, 1);          // partner feature (all lanes exec)
            if (evenl) {
                unsigned u = bf16rne(v) | (bf16rne(p) << 16);
                H2[(size_t)gr * 64 + ct * 8 + (ccol >> 1)] = u;
            }
        }
    }
}

// standalone GEMM (layer 2)
__global__ __launch_bounds__(256) void gemm_mfma(const float* __restrict__ X,
                                                 const short8* __restrict__ Wsw,
                                                 unsigned* __restrict__ H2,
                                                 int K, int kfull, int k32) {
    gemm_body(blockIdx.x, X, Wsw, H2, K, kfull, k32);
}

// ---------------- fused launch: bucket_scatter blocks || gemm1 blocks ----------------
// Scatter blocks [0, NSCAT): R10 bucketed scatter (reg-cached edges, 4B packed entry).
// The LAST scatter block to finish (device-scope done counter + threadfence) runs the
// bucket scan inline (atomic-coherent gcur reads) -> saves the bucket_scan launch.
// Gemm blocks [NSCAT, NSCAT + n/64): layer-1 X@W1, fully independent of the CSR.
__global__ __launch_bounds__(256) void scatter_gemm(const int* __restrict__ src,
                                                    const int* __restrict__ dst,
                                                    int* __restrict__ gcur,
                                                    unsigned* __restrict__ bucketed,
                                                    int E, int n, int NB, int NSCAT,
                                                    int* __restrict__ done,
                                                    int* __restrict__ bb,
                                                    int* __restrict__ rowptr,
                                                    const float* __restrict__ X,
                                                    const short8* __restrict__ Wsw,
                                                    unsigned* __restrict__ H2,
                                                    int K, int kfull, int k32) {
    __shared__ int hist[MAXNB];
    __shared__ int base[MAXNB];
    __shared__ int lcur[MAXNB];
    int bid = blockIdx.x;
    if (bid >= NSCAT) {                      // ---- gemm branch ----
        gemm_body(bid - NSCAT, X, Wsw, H2, K, kfull, k32);
        return;
    }
    // ---- scatter branch ----
    int tid = threadIdx.x;
    long e0 = (long)bid * EPB;
    for (int b = tid; b < NB; b += 256) { hist[b] = 0; lcur[b] = 0; }
    __syncthreads();
    int sv[EPB / 256], dv[EPB / 256];
#pragma unroll
    for (int i = 0; i < EPB / 256; ++i) {
        long e = e0 + i * 256 + tid;
        sv[i] = (e < E) ? src[e] : -1;
        dv[i] = (e < E) ? dst[e] : -1;
        if ((unsigned)dv[i] < (unsigned)n && (unsigned)sv[i] < (unsigned)n)
            atomicAdd(&hist[dv[i] >> 8], 1);
    }
    __syncthreads();
    for (int b = tid; b < NB; b += 256) {
        int h = hist[b];
        base[b] = h ? atomicAdd(&gcur[b * 16], h) : 0;   // 64B-padded counters
    }
    __syncthreads();
#pragma unroll
    for (int i = 0; i < EPB / 256; ++i) {
        int d = dv[i], s = sv[i];
        if ((unsigned)d < (unsigned)n && (unsigned)s < (unsigned)n) {
            int bk = d >> 8;
            int idx = base[bk] + atomicAdd(&lcur[bk], 1);
            if ((unsigned)idx < (unsigned)CAP)       // never trips for random E/NB
                bucketed[(size_t)bk * CAP + idx] =
                    (unsigned)s | ((unsigned)(d & 255) << 18);
        }
    }
    // ---- last-block inline bucket scan ----
    __threadfence();                         // release this block's gcur atomics
    __syncthreads();
    __shared__ int lastf;
    if (tid == 0) lastf = (atomicAdd(done, 1) == NSCAT - 1) ? 1 : 0;
    __syncthreads();
    if (!lastf) return;
    __threadfence();                         // acquire other blocks' gcur writes
    __shared__ int part[256];
    int v[4];
    int s = 0;
#pragma unroll
    for (int i = 0; i < 4; ++i) {
        int b = tid * 4 + i;
        v[i] = (b < NB) ? atomicAdd(&gcur[b * 16], 0) : 0;   // coherent read
        s += v[i];
    }
    part[tid] = s;
    __syncthreads();
    for (int off = 1; off < 256; off <<= 1) {
        int x = (tid >= off) ? part[tid - off] : 0;
        __syncthreads();
        part[tid] += x;
        __syncthreads();
    }
    int run = part[tid] - s;                 // exclusive prefix of this thread's chunk
#pragma unroll
    for (int i = 0; i < 4; ++i) {
        int b = tid * 4 + i;
        if (b < NB) bb[b] = run;
        run += v[i];
    }
    if (tid == 255) { bb[NB] = run; rowptr[n] = run; }
}

// one block per bucket: LDS deg count -> dinv + rowptr + LDS-cursor col scatter.
__global__ __launch_bounds__(256) void build_csr(const unsigned* __restrict__ bucketed,
                                                 const int* __restrict__ bb,
                                                 float* __restrict__ dinv,
                                                 int* __restrict__ rowptr,
                                                 int* __restrict__ col, int n) {
    __shared__ int deg[NPB];
    __shared__ int scn[NPB];
    __shared__ int cur[NPB];
    int b = blockIdx.x, tid = threadIdx.x;
    int nb0 = b * NPB;
    int ebase = bb[b], cnt = bb[b + 1] - bb[b];
    deg[tid] = 0;
    __syncthreads();
    const unsigned* ep = bucketed + (size_t)b * CAP;
    for (int i = tid; i < cnt; i += 256) {
        unsigned v = ep[i];
        atomicAdd(&deg[(v >> 18) & 255], 1);
    }
    __syncthreads();
    int d = deg[tid];
    scn[tid] = d;
    __syncthreads();
    for (int off = 1; off < 256; off <<= 1) {
        int v = (tid >= off) ? scn[tid - off] : 0;
        __syncthreads();
        scn[tid] += v;
        __syncthreads();
    }
    int excl = scn[tid] - d;
    int node = nb0 + tid;
    if (node < n) {
        dinv[node] = rsqrtf((float)(d + 1));     // +1 self loop
        rowptr[node] = ebase + excl;
    }
    cur[tid] = excl;
    __syncthreads();
    for (int i = tid; i < cnt; i += 256) {
        unsigned v = ep[i];
        int p = atomicAdd(&cur[(v >> 18) & 255], 1);
        col[ebase + p] = (int)(v & 0x3FFFFu);
    }
}

// ---------------- aggregation: one wave per node (R1 structure, fabric-bound) --------
// R11: H2 is now raw bf16(X@W); per-edge dinv[src] applied via scalar s_load + fmac
// (SMEM pipe idle, VALU at 25%). Self term gets dinv[node]^2, gathered terms get
// dinv[src]*dinv[node] -> identical normalization to the reference.
__global__ __launch_bounds__(256) void agg_relu(const unsigned* __restrict__ HS2,
                                                const int* __restrict__ rowptr,
                                                const int* __restrict__ col,
                                                const float* __restrict__ dinv,
                                                const float* __restrict__ bias,
                                                float* __restrict__ Y, int n) {
    int lane = threadIdx.x & 63;
    int node = __builtin_amdgcn_readfirstlane(blockIdx.x * 4 + (threadIdx.x >> 6));
    if (node >= n) return;
    int start = __builtin_amdgcn_readfirstlane(rowptr[node]);
    int end   = __builtin_amdgcn_readfirstlane(rowptr[node + 1]);
    float dn = dinv[node];                       // scalar
    float2 acc;
    {
        float f0, f1;
        bf2_unpack(HS2[(size_t)node * 64 + lane], f0, f1);   // self loop
        acc.x = f0 * dn; acc.y = f1 * dn;        // self gets dinv^2 after final scale
    }
    int j = start;
    for (; j + 16 <= end; j += 16) {               // 16 gathers in flight
        unsigned uv[16];
        float dq[16];
#pragma unroll
        for (int q = 0; q < 16; ++q) {
            int c = col[j + q];                    // uniform addr -> s_load
            dq[q] = dinv[c];                       // uniform -> s_load (SGPR)
            uv[q] = HS2[(size_t)c * 64 + lane];    // saddr gather, 256B/wave
        }
#pragma unroll
        for (int q = 0; q < 16; ++q) {
            float f0, f1; bf2_unpack(uv[q], f0, f1);
            acc.x = fmaf(f0, dq[q], acc.x);
            acc.y = fmaf(f1, dq[q], acc.y);
        }
    }
    while (j < end) {                              // uniform masked tail, 8-deep
        unsigned uv[8];
        float dq[8];
#pragma unroll
        for (int q = 0; q < 8; ++q) {
            int jq = j + q;
            int c = (jq < end) ? col[jq] : node;   // uniform select, safe row
            dq[q] = dinv[c];
            uv[q] = HS2[(size_t)c * 64 + lane];
        }
#pragma unroll
        for (int q = 0; q < 8; ++q) {
            unsigned u = (j + q < end) ? uv[q] : 0u;   // zero -> adds +0.0f
            float f0, f1; bf2_unpack(u, f0, f1);
            acc.x = fmaf(f0, dq[q], acc.x);
            acc.y = fmaf(f1, dq[q], acc.y);
        }
        j += 8;
    }
    float2 b = *(const float2*)&bias[2 * lane];
    float2 o;
    o.x = fmaxf(acc.x * dn + b.x, 0.f);
    o.y = fmaxf(acc.y * dn + b.y, 0.f);
    *(float2*)&Y[(long)node * HID + 2 * lane] = o;
}

// ---------------- fused layer-2 aggregation + relu + head ----------------
__global__ __launch_bounds__(256) void agg_relu_head(const unsigned* __restrict__ HS2,
                                                     const int* __restrict__ rowptr,
                                                     const int* __restrict__ col,
                                                     const float* __restrict__ dinv,
                                                     const float* __restrict__ bias,
                                                     const float* __restrict__ Wl,
                                                     const float* __restrict__ bl,
                                                     float* __restrict__ out, int n) {
    int lane = threadIdx.x & 63;
    int node = __builtin_amdgcn_readfirstlane(blockIdx.x * 4 + (threadIdx.x >> 6));
    if (node >= n) return;
    int start = __builtin_amdgcn_readfirstlane(rowptr[node]);
    int end   = __builtin_amdgcn_readfirstlane(rowptr[node + 1]);
    float dn = dinv[node];
    float2 acc;
    {
        float f0, f1;
        bf2_unpack(HS2[(size_t)node * 64 + lane], f0, f1);   // self loop
        acc.x = f0 * dn; acc.y = f1 * dn;
    }
    int j = start;
    for (; j + 16 <= end; j += 16) {
        unsigned uv[16];
        float dq[16];
#pragma unroll
        for (int q = 0; q < 16; ++q) {
            int c = col[j + q];                    // uniform addr -> s_load
            dq[q] = dinv[c];
            uv[q] = HS2[(size_t)c * 64 + lane];
        }
#pragma unroll
        for (int q = 0; q < 16; ++q) {
            float f0, f1; bf2_unpack(uv[q], f0, f1);
            acc.x = fmaf(f0, dq[q], acc.x);
            acc.y = fmaf(f1, dq[q], acc.y);
        }
    }
    while (j < end) {
        unsigned uv[8];
        float dq[8];
#pragma unroll
        for (int q = 0; q < 8; ++q) {
            int jq = j + q;
            int c = (jq < end) ? col[jq] : node;
            dq[q] = dinv[c];
            uv[q] = HS2[(size_t)c * 64 + lane];
        }
#pragma unroll
        for (int q = 0; q < 8; ++q) {
            unsigned u = (j + q < end) ? uv[q] : 0u;
            float f0, f1; bf2_unpack(u, f0, f1);
            acc.x = fmaf(f0, dq[q], acc.x);
            acc.y = fmaf(f1, dq[q], acc.y);
        }
        j += 8;
    }
    float2 b = *(const float2*)&bias[2 * lane];
    float vx = fmaxf(acc.x * dn + b.x, 0.f);   // feature 2*lane
    float vy = fmaxf(acc.y * dn + b.y, 0.f);   // feature 2*lane+1
    float4 wl = *(const float4*)&Wl[4 * lane];
    float a0 = vx * wl.x + vy * wl.z;
    float a1 = vx * wl.y + vy * wl.w;
#pragma unroll
    for (int off = 32; off > 0; off >>= 1) {
        a0 += __shfl_xor(a0, off);
        a1 += __shfl_xor(a1, off);
    }
    if (lane == 0) {
        out[(long)node * 2 + 0] = a0 + bl[0];
        out[(long)node * 2 + 1] = a1 + bl[1];
    }
}

// ---------------- launch ----------------
extern "C" void kernel_launch(void* const* d_in, const int* in_sizes, int n_in,
                              void* d_out, int out_size, void* d_ws, size_t ws_size,
                              hipStream_t stream) {
    const float* x  = (const float*)d_in[0];
    const int*   ei = (const int*)d_in[1];
    const float* W1 = (const float*)d_in[2];
    const float* b1 = (const float*)d_in[3];
    const float* W2 = (const float*)d_in[4];
    const float* b2 = (const float*)d_in[5];
    const float* Wl = (const float*)d_in[6];
    const float* bl = (const float*)d_in[7];
    float* out = (float*)d_out;

    int n = in_sizes[0] / FIN;          // 200000
    int E = in_sizes[1] / 2;            // 3200000
    int NB = (n + NPB - 1) / NPB;       // 782 buckets
    int NSCAT = (E + EPB - 1) / EPB;    // 1563 scatter blocks
    const int* srcp = ei;
    const int* dstp = ei + E;

    char* w = (char*)d_ws;
    auto alloc = [&](size_t bytes) {
        char* p = w;
        w += (bytes + 255) & ~(size_t)255;
        return (void*)p;
    };
    int*      gcur    = (int*)     alloc(((size_t)NB * 16 + 16) * 4);  // + done counter
    int*      bb      = (int*)     alloc(((size_t)NB + 1) * 4);
    int*      rowptr  = (int*)     alloc(((size_t)n + 1) * 4);
    float*    dinv    = (float*)   alloc((size_t)n * 4);
    int*      colv    = (int*)     alloc((size_t)E * 4);
    unsigned* hbuf    = (unsigned*)alloc((size_t)n * 64 * 4);    // bf16-packed HS (51 MB)
    float*    ybuf    = (float*)   alloc((size_t)n * HID * 4);
    short8*   w1sw    = (short8*)  alloc((size_t)2 * K32C1 * 8 * 64 * 16);
    short8*   w2sw    = (short8*)  alloc((size_t)2 * K32C2 * 8 * 64 * 16);
    // bucketed packed words (14.4 MB) alias ybuf (102 MB): ybuf dead until agg_relu
    // writes it, and bucketed is dead after build_csr (which precedes agg_relu).
    unsigned* bucketed = (unsigned*)ybuf;
    int*      done     = gcur + (size_t)NB * 16;

    hipMemsetAsync(gcur, 0, ((size_t)NB * 16 + 16) * 4, stream);

    // W pre-swizzle (one tiny launch for both weights)
    wswz_both<<<20, 256, 0, stream>>>(W1, w1sw, W2, w2sw);

    // fused: bucket scatter (with inline last-block scan) || layer-1 GEMM
    scatter_gemm<<<NSCAT + n / 64, 256, 0, stream>>>(srcp, dstp, gcur, bucketed,
                                                     E, n, NB, NSCAT, done, bb, rowptr,
                                                     x, w1sw, hbuf, FIN, FIN / 32, K32C1);
    build_csr<<<NB, 256, 0, stream>>>(bucketed, bb, dinv, rowptr, colv, n);

    // layer 1 aggregation: y1 = relu(dinv_d*(dinv_d*h_d + sum dinv_s*h_s) + b1)
    agg_relu<<<(n + 3) / 4, 256, 0, stream>>>(hbuf, rowptr, colv, dinv, b1, ybuf, n);

    // layer 2 GEMM (reads fp32 ybuf, writes raw bf16-packed hbuf)
    gemm_mfma<<<n / 64, 256, 0, stream>>>(ybuf, w2sw, hbuf, HID, HID / 32, K32C2);

    // fused layer-2 aggregation + relu + head
    agg_relu_head<<<(n + 3) / 4, 256, 0, stream>>>(hbuf, rowptr, colv, dinv, b2,
                                                   Wl, bl, out, n);
}

// Round 8
// 787.558 us; speedup vs baseline: 1.3312x; 1.3312x over previous
//
#include <hip/hip_runtime.h>
#include <hip/hip_bf16.h>

// ---------------- problem constants ----------------
#define FIN 165
#define HID 128
#define NPB 256        // nodes per bucket (bucket = dst >> 8)
#define MAXNB 784      // max bucket count (n=200000 -> 782)
#define CAP 4608       // bucket slot capacity (avg 4093, sigma~64 -> 8 sigma slack)
#define EPB 2048       // edges per scatter block
#define K32C1 6        // ceil(FIN/32)
#define K32C2 4        // HID/32

typedef __attribute__((ext_vector_type(8))) short short8;   // 8 bf16 (4 VGPRs)
typedef __attribute__((ext_vector_type(4))) float float4v;  // 4 fp32 acc

// round-to-nearest-even fp32 -> bf16 (returns low 16 bits)
__device__ inline unsigned bf16rne(float v) {
    unsigned u = __float_as_uint(v);
    return (u + 0x7fffu + ((u >> 16) & 1u)) >> 16;
}

// round-to-nearest-even fp32 -> bf16 split: v ~= hi + lo, residual ~ 2^-18 |v|
__device__ inline void bf16split(float v, short& h, short& l) {
    unsigned u = __float_as_uint(v);
    unsigned r = u + 0x7fffu + ((u >> 16) & 1u);
    h = (short)(r >> 16);
    float hf = __uint_as_float(((unsigned)(unsigned short)h) << 16);
    float lf = v - hf;                       // exact in fp32
    unsigned u2 = __float_as_uint(lf);
    unsigned r2 = u2 + 0x7fffu + ((u2 >> 16) & 1u);
    l = (short)(r2 >> 16);
}

// unpack packed bf16 pair -> two fp32
__device__ inline void bf2_unpack(unsigned u, float& f0, float& f1) {
    f0 = __uint_as_float(u << 16);
    f1 = __uint_as_float(u & 0xffff0000u);
}

// ---------------- W swizzle: fp32 [K x 128] -> bf16 hi/lo in MFMA B-frag order --------
__device__ inline void wswz_body(const float* W, short8* out, int K, int k32, int idx) {
    int tot = k32 * 8 * 64;
    if (idx >= tot) return;
    int lane = idx & 63;
    int ct = (idx >> 6) & 7;
    int ks = idx >> 9;
    int col = ct * 16 + (lane & 15);
    int kb = ks * 32 + (lane >> 4) * 8;
    short8 hi, lo;
#pragma unroll
    for (int j = 0; j < 8; ++j) {
        int k = kb + j;
        float v = (k < K) ? W[k * HID + col] : 0.f;
        short h, l;
        bf16split(v, h, l);
        hi[j] = h; lo[j] = l;
    }
    out[idx] = hi;
    out[tot + idx] = lo;
}

__global__ __launch_bounds__(256) void wswz_both(const float* __restrict__ W1p,
                                                 short8* __restrict__ o1,
                                                 const float* __restrict__ W2p,
                                                 short8* __restrict__ o2) {
    int bid = blockIdx.x;
    if (bid < 12) wswz_body(W1p, o1, FIN, K32C1, bid * 256 + threadIdx.x);
    else          wswz_body(W2p, o2, HID, K32C2, (bid - 12) * 256 + threadIdx.x);
}

// ---------------- bucketed CSR build (R10 kernels, unchanged) ----------------
__global__ __launch_bounds__(256) void bucket_scatter(const int* __restrict__ src,
                                                      const int* __restrict__ dst,
                                                      int* __restrict__ gcur,
                                                      unsigned* __restrict__ bucketed,
                                                      int E, int n, int NB) {
    __shared__ int hist[MAXNB];
    __shared__ int base[MAXNB];
    __shared__ int lcur[MAXNB];
    int tid = threadIdx.x;
    long e0 = (long)blockIdx.x * EPB;
    for (int b = tid; b < NB; b += 256) { hist[b] = 0; lcur[b] = 0; }
    __syncthreads();
    int sv[EPB / 256], dv[EPB / 256];
#pragma unroll
    for (int i = 0; i < EPB / 256; ++i) {
        long e = e0 + i * 256 + tid;
        sv[i] = (e < E) ? src[e] : -1;
        dv[i] = (e < E) ? dst[e] : -1;
        if ((unsigned)dv[i] < (unsigned)n && (unsigned)sv[i] < (unsigned)n)
            atomicAdd(&hist[dv[i] >> 8], 1);
    }
    __syncthreads();
    for (int b = tid; b < NB; b += 256) {
        int h = hist[b];
        base[b] = h ? atomicAdd(&gcur[b * 16], h) : 0;   // 64B-padded counters
    }
    __syncthreads();
#pragma unroll
    for (int i = 0; i < EPB / 256; ++i) {
        int d = dv[i], s = sv[i];
        if ((unsigned)d < (unsigned)n && (unsigned)s < (unsigned)n) {
            int bk = d >> 8;
            int idx = base[bk] + atomicAdd(&lcur[bk], 1);
            if ((unsigned)idx < (unsigned)CAP)       // never trips for random E/NB
                bucketed[(size_t)bk * CAP + idx] =
                    (unsigned)s | ((unsigned)(d & 255) << 18);
        }
    }
}

// exclusive scan of bucket counts (parallel Hillis-Steele)
__global__ __launch_bounds__(256) void bucket_scan(const int* __restrict__ gcur,
                                                   int* __restrict__ bb, int NB,
                                                   int* __restrict__ rowptr, int n) {
    __shared__ int part[256];
    int t = threadIdx.x;
    int v[4];
    int s = 0;
#pragma unroll
    for (int i = 0; i < 4; ++i) {
        int b = t * 4 + i;
        v[i] = (b < NB) ? gcur[b * 16] : 0;
        s += v[i];
    }
    part[t] = s;
    __syncthreads();
    for (int off = 1; off < 256; off <<= 1) {
        int x = (t >= off) ? part[t - off] : 0;
        __syncthreads();
        part[t] += x;
        __syncthreads();
    }
    int run = part[t] - s;                   // exclusive prefix of this thread's chunk
#pragma unroll
    for (int i = 0; i < 4; ++i) {
        int b = t * 4 + i;
        if (b < NB) bb[b] = run;
        run += v[i];
    }
    if (t == 255) { bb[NB] = run; rowptr[n] = run; }
}

// ---------------- MFMA GEMM body ----------------
// dinvp == nullptr -> raw bf16(X@W) (layer 1, CSR-independent, fusable);
// dinvp != nullptr -> pre-scaled by dinv[row] (layer 2, R6 behavior).
__device__ void gemm_body(int bid, const float* __restrict__ X,
                          const short8* __restrict__ Wsw,
                          const float* __restrict__ dinvp,
                          unsigned* __restrict__ H2, int K, int kfull, int k32) {
    int wave = threadIdx.x >> 6, lane = threadIdx.x & 63;
    int r0 = bid * 64 + wave * 16;
    int m = lane & 15, kph = lane >> 4;
    int row = r0 + m;
    const float* xrow = X + (size_t)row * K + kph * 8;
    const short8* Whi = Wsw;
    const short8* Wlo = Wsw + (size_t)k32 * 8 * 64;

    float4v acc[8];
#pragma unroll
    for (int ct = 0; ct < 8; ++ct) acc[ct] = (float4v){0.f, 0.f, 0.f, 0.f};

    for (int ks = 0; ks < kfull; ++ks) {
        float xv[8];
#pragma unroll
        for (int j = 0; j < 8; ++j) xv[j] = xrow[ks * 32 + j];
        short8 ah, al;
#pragma unroll
        for (int j = 0; j < 8; ++j) {
            short h, l; bf16split(xv[j], h, l);
            ah[j] = h; al[j] = l;
        }
#pragma unroll
        for (int ct = 0; ct < 8; ++ct) {
            short8 bh = Whi[(ks * 8 + ct) * 64 + lane];
            short8 bl = Wlo[(ks * 8 + ct) * 64 + lane];
            acc[ct] = __builtin_amdgcn_mfma_f32_16x16x32_bf16(ah, bh, acc[ct], 0, 0, 0);
            acc[ct] = __builtin_amdgcn_mfma_f32_16x16x32_bf16(al, bh, acc[ct], 0, 0, 0);
            acc[ct] = __builtin_amdgcn_mfma_f32_16x16x32_bf16(ah, bl, acc[ct], 0, 0, 0);
        }
    }
    if (kfull < k32) {                       // K-tail (layer 1: k = 160..164)
        int ks = kfull;
        int kb = ks * 32 + kph * 8;
        float xv[8];
#pragma unroll
        for (int j = 0; j < 8; ++j) xv[j] = (kb + j < K) ? xrow[ks * 32 + j] : 0.f;
        short8 ah, al;
#pragma unroll
        for (int j = 0; j < 8; ++j) {
            short h, l; bf16split(xv[j], h, l);
            ah[j] = h; al[j] = l;
        }
#pragma unroll
        for (int ct = 0; ct < 8; ++ct) {
            short8 bh = Whi[(ks * 8 + ct) * 64 + lane];
            short8 bl = Wlo[(ks * 8 + ct) * 64 + lane];
            acc[ct] = __builtin_amdgcn_mfma_f32_16x16x32_bf16(ah, bh, acc[ct], 0, 0, 0);
            acc[ct] = __builtin_amdgcn_mfma_f32_16x16x32_bf16(al, bh, acc[ct], 0, 0, 0);
            acc[ct] = __builtin_amdgcn_mfma_f32_16x16x32_bf16(ah, bl, acc[ct], 0, 0, 0);
        }
    }
    // epilogue: C/D layout col=lane&15, row=(lane>>4)*4+reg  [m89-verified]
    int ccol = lane & 15, crow = (lane >> 4) * 4;
    bool evenl = (ccol & 1) == 0;
#pragma unroll
    for (int r = 0; r < 4; ++r) {
        int gr = r0 + crow + r;
        float s = dinvp ? dinvp[gr] : 1.0f;
#pragma unroll
        for (int ct = 0; ct < 8; ++ct) {
            float v = acc[ct][r] * s;
            float p = __shfl_xor(v, 1);          // partner feature (all lanes exec)
            if (evenl) {
                unsigned u = bf16rne(v) | (bf16rne(p) << 16);
                H2[(size_t)gr * 64 + ct * 8 + (ccol >> 1)] = u;
            }
        }
    }
}

// standalone GEMM (layer 2, dinv pre-scaled)
__global__ __launch_bounds__(256) void gemm_mfma(const float* __restrict__ X,
                                                 const short8* __restrict__ Wsw,
                                                 const float* __restrict__ dinv,
                                                 unsigned* __restrict__ H2,
                                                 int K, int kfull, int k32) {
    gemm_body(blockIdx.x, X, Wsw, dinv, H2, K, kfull, k32);
}

// ---------------- build_csr body (R10, unchanged) ----------------
__device__ void build_csr_body(int b, const unsigned* __restrict__ bucketed,
                               const int* __restrict__ bb,
                               float* __restrict__ dinv,
                               int* __restrict__ rowptr,
                               int* __restrict__ col, int n) {
    __shared__ int deg[NPB];
    __shared__ int scn[NPB];
    __shared__ int cur[NPB];
    int tid = threadIdx.x;
    int nb0 = b * NPB;
    int ebase = bb[b], cnt = bb[b + 1] - bb[b];
    deg[tid] = 0;
    __syncthreads();
    const unsigned* ep = bucketed + (size_t)b * CAP;
    for (int i = tid; i < cnt; i += 256) {
        unsigned v = ep[i];
        atomicAdd(&deg[(v >> 18) & 255], 1);
    }
    __syncthreads();
    int d = deg[tid];
    scn[tid] = d;
    __syncthreads();
    for (int off = 1; off < 256; off <<= 1) {
        int v = (tid >= off) ? scn[tid - off] : 0;
        __syncthreads();
        scn[tid] += v;
        __syncthreads();
    }
    int excl = scn[tid] - d;
    int node = nb0 + tid;
    if (node < n) {
        dinv[node] = rsqrtf((float)(d + 1));     // +1 self loop
        rowptr[node] = ebase + excl;
    }
    cur[tid] = excl;
    __syncthreads();
    for (int i = tid; i < cnt; i += 256) {
        unsigned v = ep[i];
        int p = atomicAdd(&cur[(v >> 18) & 255], 1);
        col[ebase + p] = (int)(v & 0x3FFFFu);
    }
}

// ---------------- fused launch: build_csr blocks || layer-1 GEMM blocks --------------
// R12: NO inter-block communication, NO fences (R7 lesson: per-block device fences =
// L2 writeback storm). csr reads bb/bucketed from PREVIOUS launches; gemm reads X/W1.
// csr blocks first (latency-bound, overlap with compute-bound gemm blocks on each CU).
__global__ __launch_bounds__(256) void csr_gemm(const unsigned* __restrict__ bucketed,
                                                const int* __restrict__ bb,
                                                float* __restrict__ dinv,
                                                int* __restrict__ rowptr,
                                                int* __restrict__ col, int n, int NCSR,
                                                const float* __restrict__ X,
                                                const short8* __restrict__ Wsw,
                                                unsigned* __restrict__ H2,
                                                int K, int kfull, int k32) {
    int bid = blockIdx.x;
    if (bid < NCSR) build_csr_body(bid, bucketed, bb, dinv, rowptr, col, n);
    else            gemm_body(bid - NCSR, X, Wsw, nullptr, H2, K, kfull, k32);
}

// ---------------- layer-1 aggregation: per-edge dinv (H2 is raw bf16(X@W1)) ----------
// Self term: dinv^2 * h_self; gathered: dinv[dst]*dinv[src]*h_src — identical math to
// the reference. dinv[c] is wave-uniform -> s_load (SMEM pipe idle at 25% VALU).
__global__ __launch_bounds__(256) void agg_relu(const unsigned* __restrict__ HS2,
                                                const int* __restrict__ rowptr,
                                                const int* __restrict__ col,
                                                const float* __restrict__ dinv,
                                                const float* __restrict__ bias,
                                                float* __restrict__ Y, int n) {
    int lane = threadIdx.x & 63;
    int node = __builtin_amdgcn_readfirstlane(blockIdx.x * 4 + (threadIdx.x >> 6));
    if (node >= n) return;
    int start = __builtin_amdgcn_readfirstlane(rowptr[node]);
    int end   = __builtin_amdgcn_readfirstlane(rowptr[node + 1]);
    float dn = dinv[node];                       // scalar
    float2 acc;
    {
        float f0, f1;
        bf2_unpack(HS2[(size_t)node * 64 + lane], f0, f1);   // self loop
        acc.x = f0 * dn; acc.y = f1 * dn;        // self gets dinv^2 after final scale
    }
    int j = start;
    for (; j + 16 <= end; j += 16) {               // 16 gathers in flight
        unsigned uv[16];
        float dq[16];
#pragma unroll
        for (int q = 0; q < 16; ++q) {
            int c = col[j + q];                    // uniform addr -> s_load
            dq[q] = dinv[c];                       // uniform -> s_load (SGPR)
            uv[q] = HS2[(size_t)c * 64 + lane];    // saddr gather, 256B/wave
        }
#pragma unroll
        for (int q = 0; q < 16; ++q) {
            float f0, f1; bf2_unpack(uv[q], f0, f1);
            acc.x = fmaf(f0, dq[q], acc.x);
            acc.y = fmaf(f1, dq[q], acc.y);
        }
    }
    while (j < end) {                              // uniform masked tail, 8-deep
        unsigned uv[8];
        float dq[8];
#pragma unroll
        for (int q = 0; q < 8; ++q) {
            int jq = j + q;
            int c = (jq < end) ? col[jq] : node;   // uniform select, safe row
            dq[q] = dinv[c];
            uv[q] = HS2[(size_t)c * 64 + lane];
        }
#pragma unroll
        for (int q = 0; q < 8; ++q) {
            unsigned u = (j + q < end) ? uv[q] : 0u;   // zero -> adds +0.0f
            float f0, f1; bf2_unpack(u, f0, f1);
            acc.x = fmaf(f0, dq[q], acc.x);
            acc.y = fmaf(f1, dq[q], acc.y);
        }
        j += 8;
    }
    float2 b = *(const float2*)&bias[2 * lane];
    float2 o;
    o.x = fmaxf(acc.x * dn + b.x, 0.f);
    o.y = fmaxf(acc.y * dn + b.y, 0.f);
    *(float2*)&Y[(long)node * HID + 2 * lane] = o;
}

// ---------------- fused layer-2 aggregation + relu + head (R6 exact) ----------------
__global__ __launch_bounds__(256) void agg_relu_head(const unsigned* __restrict__ HS2,
                                                     const int* __restrict__ rowptr,
                                                     const int* __restrict__ col,
                                                     const float* __restrict__ dinv,
                                                     const float* __restrict__ bias,
                                                     const float* __restrict__ Wl,
                                                     const float* __restrict__ bl,
                                                     float* __restrict__ out, int n) {
    int lane = threadIdx.x & 63;
    int node = __builtin_amdgcn_readfirstlane(blockIdx.x * 4 + (threadIdx.x >> 6));
    if (node >= n) return;
    int start = __builtin_amdgcn_readfirstlane(rowptr[node]);
    int end   = __builtin_amdgcn_readfirstlane(rowptr[node + 1]);
    float2 acc;
    {
        float f0, f1;
        bf2_unpack(HS2[(size_t)node * 64 + lane], f0, f1);   // self loop
        acc.x = f0; acc.y = f1;
    }
    int j = start;
    for (; j + 16 <= end; j += 16) {
        unsigned uv[16];
#pragma unroll
        for (int q = 0; q < 16; ++q) {
            int c = col[j + q];                    // uniform addr -> s_load
            uv[q] = HS2[(size_t)c * 64 + lane];
        }
#pragma unroll
        for (int q = 0; q < 16; ++q) {
            float f0, f1; bf2_unpack(uv[q], f0, f1);
            acc.x += f0; acc.y += f1;
        }
    }
    while (j < end) {
        unsigned uv[8];
#pragma unroll
        for (int q = 0; q < 8; ++q) {
            int jq = j + q;
            int c = (jq < end) ? col[jq] : node;
            uv[q] = HS2[(size_t)c * 64 + lane];
        }
#pragma unroll
        for (int q = 0; q < 8; ++q) {
            unsigned u = (j + q < end) ? uv[q] : 0u;
            float f0, f1; bf2_unpack(u, f0, f1);
            acc.x += f0; acc.y += f1;
        }
        j += 8;
    }
    float s = dinv[node];
    float2 b = *(const float2*)&bias[2 * lane];
    float vx = fmaxf(acc.x * s + b.x, 0.f);   // feature 2*lane
    float vy = fmaxf(acc.y * s + b.y, 0.f);   // feature 2*lane+1
    float4 wl = *(const float4*)&Wl[4 * lane];
    float a0 = vx * wl.x + vy * wl.z;
    float a1 = vx * wl.y + vy * wl.w;
#pragma unroll
    for (int off = 32; off > 0; off >>= 1) {
        a0 += __shfl_xor(a0, off);
        a1 += __shfl_xor(a1, off);
    }
    if (lane == 0) {
        out[(long)node * 2 + 0] = a0 + bl[0];
        out[(long)node * 2 + 1] = a1 + bl[1];
    }
}

// ---------------- launch ----------------
extern "C" void kernel_launch(void* const* d_in, const int* in_sizes, int n_in,
                              void* d_out, int out_size, void* d_ws, size_t ws_size,
                              hipStream_t stream) {
    const float* x  = (const float*)d_in[0];
    const int*   ei = (const int*)d_in[1];
    const float* W1 = (const float*)d_in[2];
    const float* b1 = (const float*)d_in[3];
    const float* W2 = (const float*)d_in[4];
    const float* b2 = (const float*)d_in[5];
    const float* Wl = (const float*)d_in[6];
    const float* bl = (const float*)d_in[7];
    float* out = (float*)d_out;

    int n = in_sizes[0] / FIN;          // 200000
    int E = in_sizes[1] / 2;            // 3200000
    int NB = (n + NPB - 1) / NPB;       // 782 buckets
    const int* srcp = ei;
    const int* dstp = ei + E;

    char* w = (char*)d_ws;
    auto alloc = [&](size_t bytes) {
        char* p = w;
        w += (bytes + 255) & ~(size_t)255;
        return (void*)p;
    };
    int*      gcur    = (int*)     alloc((size_t)NB * 16 * 4);   // 64B-padded cursors
    int*      bb      = (int*)     alloc(((size_t)NB + 1) * 4);
    int*      rowptr  = (int*)     alloc(((size_t)n + 1) * 4);
    float*    dinv    = (float*)   alloc((size_t)n * 4);
    int*      colv    = (int*)     alloc((size_t)E * 4);
    unsigned* hbuf    = (unsigned*)alloc((size_t)n * 64 * 4);    // bf16-packed HS (51 MB)
    float*    ybuf    = (float*)   alloc((size_t)n * HID * 4);
    short8*   w1sw    = (short8*)  alloc((size_t)2 * K32C1 * 8 * 64 * 16);
    short8*   w2sw    = (short8*)  alloc((size_t)2 * K32C2 * 8 * 64 * 16);
    // bucketed packed words (14.4 MB) alias ybuf (102 MB): ybuf dead until agg_relu
    // writes it, and bucketed is dead after csr_gemm (which precedes agg_relu).
    unsigned* bucketed = (unsigned*)ybuf;

    hipMemsetAsync(gcur, 0, (size_t)NB * 16 * 4, stream);

    // W pre-swizzle (one tiny launch for both weights)
    wswz_both<<<20, 256, 0, stream>>>(W1, w1sw, W2, w2sw);

    // bucketed CSR build (separate launches -> launch-boundary coherence, no fences)
    bucket_scatter<<<(E + EPB - 1) / EPB, 256, 0, stream>>>(srcp, dstp, gcur,
                                                            bucketed, E, n, NB);
    bucket_scan<<<1, 256, 0, stream>>>(gcur, bb, NB, rowptr, n);

    // fused: build_csr (782 blocks) || layer-1 GEMM raw (3125 blocks)
    csr_gemm<<<NB + n / 64, 256, 0, stream>>>(bucketed, bb, dinv, rowptr, colv, n, NB,
                                              x, w1sw, hbuf, FIN, FIN / 32, K32C1);

    // layer 1 aggregation: y1 = relu(dinv_d*(dinv_d*h_d + sum dinv_s*h_s) + b1)
    agg_relu<<<(n + 3) / 4, 256, 0, stream>>>(hbuf, rowptr, colv, dinv, b1, ybuf, n);

    // layer 2 GEMM (reads fp32 ybuf, writes dinv-scaled bf16-packed hbuf)
    gemm_mfma<<<n / 64, 256, 0, stream>>>(ybuf, w2sw, dinv, hbuf, HID, HID / 32, K32C2);

    // fused layer-2 aggregation + relu + head (R6 exact)
    agg_relu_head<<<(n + 3) / 4, 256, 0, stream>>>(hbuf, rowptr, colv, dinv, b2,
                                                   Wl, bl, out, n);
}

// Round 10
// 672.068 us; speedup vs baseline: 1.5600x; 1.1718x over previous
//
#include <hip/hip_runtime.h>
#include <hip/hip_bf16.h>

// ---------------- problem constants ----------------
#define FIN 165
#define HID 128
#define NPB 256        // nodes per bucket (bucket = dst >> 8)
#define MAXNB 784      // max bucket count (n=200000 -> 782)
#define CAP 4608       // bucket slot capacity (avg 4093, sigma~64 -> 8 sigma slack)
#define EPB 2048       // edges per scatter block
#define K32C1 6        // ceil(FIN/32)
#define K32C2 4        // HID/32

typedef __attribute__((ext_vector_type(8))) short short8;   // 8 bf16 (4 VGPRs)
typedef __attribute__((ext_vector_type(4))) float float4v;  // 4 fp32 acc

// round-to-nearest-even fp32 -> bf16 (returns low 16 bits)
__device__ inline unsigned bf16rne(float v) {
    unsigned u = __float_as_uint(v);
    return (u + 0x7fffu + ((u >> 16) & 1u)) >> 16;
}

// round-to-nearest-even fp32 -> bf16 split: v ~= hi + lo, residual ~ 2^-18 |v|
__device__ inline void bf16split(float v, short& h, short& l) {
    unsigned u = __float_as_uint(v);
    unsigned r = u + 0x7fffu + ((u >> 16) & 1u);
    h = (short)(r >> 16);
    float hf = __uint_as_float(((unsigned)(unsigned short)h) << 16);
    float lf = v - hf;                       // exact in fp32
    unsigned u2 = __float_as_uint(lf);
    unsigned r2 = u2 + 0x7fffu + ((u2 >> 16) & 1u);
    l = (short)(r2 >> 16);
}

// unpack packed bf16 pair -> two fp32
__device__ inline void bf2_unpack(unsigned u, float& f0, float& f1) {
    f0 = __uint_as_float(u << 16);
    f1 = __uint_as_float(u & 0xffff0000u);
}

// ---------------- W swizzle: fp32 [K x 128] -> bf16 hi/lo in MFMA B-frag order --------
__device__ inline void wswz_body(const float* W, short8* out, int K, int k32, int idx) {
    int tot = k32 * 8 * 64;
    if (idx >= tot) return;
    int lane = idx & 63;
    int ct = (idx >> 6) & 7;
    int ks = idx >> 9;
    int col = ct * 16 + (lane & 15);
    int kb = ks * 32 + (lane >> 4) * 8;
    short8 hi, lo;
#pragma unroll
    for (int j = 0; j < 8; ++j) {
        int k = kb + j;
        float v = (k < K) ? W[k * HID + col] : 0.f;
        short h, l;
        bf16split(v, h, l);
        hi[j] = h; lo[j] = l;
    }
    out[idx] = hi;
    out[tot + idx] = lo;
}

__global__ __launch_bounds__(256) void wswz_both(const float* __restrict__ W1p,
                                                 short8* __restrict__ o1,
                                                 const float* __restrict__ W2p,
                                                 short8* __restrict__ o2) {
    int bid = blockIdx.x;
    if (bid < 12) wswz_body(W1p, o1, FIN, K32C1, bid * 256 + threadIdx.x);
    else          wswz_body(W2p, o2, HID, K32C2, (bid - 12) * 256 + threadIdx.x);
}

// ---------------- bucketed CSR build (R10 kernels, unchanged) ----------------
__global__ __launch_bounds__(256) void bucket_scatter(const int* __restrict__ src,
                                                      const int* __restrict__ dst,
                                                      int* __restrict__ gcur,
                                                      unsigned* __restrict__ bucketed,
                                                      int E, int n, int NB) {
    __shared__ int hist[MAXNB];
    __shared__ int base[MAXNB];
    __shared__ int lcur[MAXNB];
    int tid = threadIdx.x;
    long e0 = (long)blockIdx.x * EPB;
    for (int b = tid; b < NB; b += 256) { hist[b] = 0; lcur[b] = 0; }
    __syncthreads();
    int sv[EPB / 256], dv[EPB / 256];
#pragma unroll
    for (int i = 0; i < EPB / 256; ++i) {
        long e = e0 + i * 256 + tid;
        sv[i] = (e < E) ? src[e] : -1;
        dv[i] = (e < E) ? dst[e] : -1;
        if ((unsigned)dv[i] < (unsigned)n && (unsigned)sv[i] < (unsigned)n)
            atomicAdd(&hist[dv[i] >> 8], 1);
    }
    __syncthreads();
    for (int b = tid; b < NB; b += 256) {
        int h = hist[b];
        base[b] = h ? atomicAdd(&gcur[b * 16], h) : 0;   // 64B-padded counters
    }
    __syncthreads();
#pragma unroll
    for (int i = 0; i < EPB / 256; ++i) {
        int d = dv[i], s = sv[i];
        if ((unsigned)d < (unsigned)n && (unsigned)s < (unsigned)n) {
            int bk = d >> 8;
            int idx = base[bk] + atomicAdd(&lcur[bk], 1);
            if ((unsigned)idx < (unsigned)CAP)       // never trips for random E/NB
                bucketed[(size_t)bk * CAP + idx] =
                    (unsigned)s | ((unsigned)(d & 255) << 18);
        }
    }
}

// exclusive scan of bucket counts (parallel Hillis-Steele)
__global__ __launch_bounds__(256) void bucket_scan(const int* __restrict__ gcur,
                                                   int* __restrict__ bb, int NB,
                                                   int* __restrict__ rowptr, int n) {
    __shared__ int part[256];
    int t = threadIdx.x;
    int v[4];
    int s = 0;
#pragma unroll
    for (int i = 0; i < 4; ++i) {
        int b = t * 4 + i;
        v[i] = (b < NB) ? gcur[b * 16] : 0;
        s += v[i];
    }
    part[t] = s;
    __syncthreads();
    for (int off = 1; off < 256; off <<= 1) {
        int x = (t >= off) ? part[t - off] : 0;
        __syncthreads();
        part[t] += x;
        __syncthreads();
    }
    int run = part[t] - s;                   // exclusive prefix of this thread's chunk
#pragma unroll
    for (int i = 0; i < 4; ++i) {
        int b = t * 4 + i;
        if (b < NB) bb[b] = run;
        run += v[i];
    }
    if (t == 255) { bb[NB] = run; rowptr[n] = run; }
}

// one block per bucket: LDS deg count -> dinv + rowptr + LDS-cursor col scatter.
__global__ __launch_bounds__(256) void build_csr(const unsigned* __restrict__ bucketed,
                                                 const int* __restrict__ bb,
                                                 float* __restrict__ dinv,
                                                 int* __restrict__ rowptr,
                                                 int* __restrict__ col, int n) {
    __shared__ int deg[NPB];
    __shared__ int scn[NPB];
    __shared__ int cur[NPB];
    int b = blockIdx.x, tid = threadIdx.x;
    int nb0 = b * NPB;
    int ebase = bb[b], cnt = bb[b + 1] - bb[b];
    deg[tid] = 0;
    __syncthreads();
    const unsigned* ep = bucketed + (size_t)b * CAP;
    for (int i = tid; i < cnt; i += 256) {
        unsigned v = ep[i];
        atomicAdd(&deg[(v >> 18) & 255], 1);
    }
    __syncthreads();
    int d = deg[tid];
    scn[tid] = d;
    __syncthreads();
    for (int off = 1; off < 256; off <<= 1) {
        int v = (tid >= off) ? scn[tid - off] : 0;
        __syncthreads();
        scn[tid] += v;
        __syncthreads();
    }
    int excl = scn[tid] - d;
    int node = nb0 + tid;
    if (node < n) {
        dinv[node] = rsqrtf((float)(d + 1));     // +1 self loop
        rowptr[node] = ebase + excl;
    }
    cur[tid] = excl;
    __syncthreads();
    for (int i = tid; i < cnt; i += 256) {
        unsigned v = ep[i];
        int p = atomicAdd(&cur[(v >> 18) & 255], 1);
        col[ebase + p] = (int)(v & 0x3FFFFu);
    }
}

// ---------------- LDS-staged MFMA GEMM: H2[r,c-pair] = bf16x2(dinv[r]*(X@W)[r,c]) -----
// R13: the old gemm re-fetched ALL of W from L2 per wave (96 x 1KB loads/wave ->
// ~1.2 GB L2 traffic, latency-bound chain; R12 PMC: MfmaUtil 6.4% => only ~12 us of
// real MFMA work inside a ~120 us kernel). Stage W-hi (and W-lo when it fits) in LDS
// once per block, grid-stride over row tiles to amortize. B-reads become ds_read_b128
// (stride-16B, conflict-free). Arithmetic identical to R6 -> absmax unchanged.
template <int K32, bool LO_IN_LDS>
__global__ __launch_bounds__(256) void gemm_lds(const float* __restrict__ X,
                                                const short8* __restrict__ Wsw,
                                                const float* __restrict__ dinv,
                                                unsigned* __restrict__ H2,
                                                int K, int kfull, int ntiles) {
    __shared__ short8 sh_hi[K32 * 8 * 64];                   // 8KB * K32
    __shared__ short8 sh_lo[LO_IN_LDS ? K32 * 8 * 64 : 1];
    const int tot = K32 * 8 * 64;
    int tid = threadIdx.x;
    for (int i = tid; i < tot; i += 256) sh_hi[i] = Wsw[i];
    if (LO_IN_LDS)
        for (int i = tid; i < tot; i += 256) sh_lo[i] = Wsw[tot + i];
    __syncthreads();
    const short8* wlo_g = Wsw + tot;

    int wave = tid >> 6, lane = tid & 63;
    int m = lane & 15, kph = lane >> 4;

    for (int t = blockIdx.x; t < ntiles; t += gridDim.x) {
        int r0 = t * 64 + wave * 16;
        int row = r0 + m;
        const float* xrow = X + (size_t)row * K + kph * 8;

        float4v acc[8];
#pragma unroll
        for (int ct = 0; ct < 8; ++ct) acc[ct] = (float4v){0.f, 0.f, 0.f, 0.f};

        for (int ks = 0; ks < kfull; ++ks) {
            float xv[8];
#pragma unroll
            for (int j = 0; j < 8; ++j) xv[j] = xrow[ks * 32 + j];
            short8 ah, al;
#pragma unroll
            for (int j = 0; j < 8; ++j) {
                short h, l; bf16split(xv[j], h, l);
                ah[j] = h; al[j] = l;
            }
#pragma unroll
            for (int ct = 0; ct < 8; ++ct) {
                short8 bh = sh_hi[(ks * 8 + ct) * 64 + lane];
                short8 bl = LO_IN_LDS ? sh_lo[(ks * 8 + ct) * 64 + lane]
                                      : wlo_g[(ks * 8 + ct) * 64 + lane];
                acc[ct] = __builtin_amdgcn_mfma_f32_16x16x32_bf16(ah, bh, acc[ct], 0, 0, 0);
                acc[ct] = __builtin_amdgcn_mfma_f32_16x16x32_bf16(al, bh, acc[ct], 0, 0, 0);
                acc[ct] = __builtin_amdgcn_mfma_f32_16x16x32_bf16(ah, bl, acc[ct], 0, 0, 0);
            }
        }
        if (kfull < K32) {                   // K-tail (layer 1: k = 160..164)
            int ks = kfull;
            int kb = ks * 32 + kph * 8;
            float xv[8];
#pragma unroll
            for (int j = 0; j < 8; ++j) xv[j] = (kb + j < K) ? xrow[ks * 32 + j] : 0.f;
            short8 ah, al;
#pragma unroll
            for (int j = 0; j < 8; ++j) {
                short h, l; bf16split(xv[j], h, l);
                ah[j] = h; al[j] = l;
            }
#pragma unroll
            for (int ct = 0; ct < 8; ++ct) {
                short8 bh = sh_hi[(ks * 8 + ct) * 64 + lane];
                short8 bl = LO_IN_LDS ? sh_lo[(ks * 8 + ct) * 64 + lane]
                                      : wlo_g[(ks * 8 + ct) * 64 + lane];
                acc[ct] = __builtin_amdgcn_mfma_f32_16x16x32_bf16(ah, bh, acc[ct], 0, 0, 0);
                acc[ct] = __builtin_amdgcn_mfma_f32_16x16x32_bf16(al, bh, acc[ct], 0, 0, 0);
                acc[ct] = __builtin_amdgcn_mfma_f32_16x16x32_bf16(ah, bl, acc[ct], 0, 0, 0);
            }
        }
        // epilogue: C/D layout col=lane&15, row=(lane>>4)*4+reg  [m89-verified]
        int ccol = lane & 15, crow = (lane >> 4) * 4;
        bool evenl = (ccol & 1) == 0;
#pragma unroll
        for (int r = 0; r < 4; ++r) {
            int gr = r0 + crow + r;
            float s = dinv[gr];
#pragma unroll
            for (int ct = 0; ct < 8; ++ct) {
                float v = acc[ct][r] * s;
                float p = __shfl_xor(v, 1);      // partner feature (all lanes exec)
                if (evenl) {
                    unsigned u = bf16rne(v) | (bf16rne(p) << 16);
                    H2[(size_t)gr * 64 + ct * 8 + (ccol >> 1)] = u;
                }
            }
        }
    }
}

// ---------------- aggregation: one wave per node (R6 exact, fabric-bound) ------------
__global__ __launch_bounds__(256) void agg_relu(const unsigned* __restrict__ HS2,
                                                const int* __restrict__ rowptr,
                                                const int* __restrict__ col,
                                                const float* __restrict__ dinv,
                                                const float* __restrict__ bias,
                                                float* __restrict__ Y, int n) {
    int lane = threadIdx.x & 63;
    int node = __builtin_amdgcn_readfirstlane(blockIdx.x * 4 + (threadIdx.x >> 6));
    if (node >= n) return;
    int start = __builtin_amdgcn_readfirstlane(rowptr[node]);
    int end   = __builtin_amdgcn_readfirstlane(rowptr[node + 1]);
    float2 acc;
    {
        float f0, f1;
        bf2_unpack(HS2[(size_t)node * 64 + lane], f0, f1);   // self loop
        acc.x = f0; acc.y = f1;
    }
    int j = start;
    for (; j + 16 <= end; j += 16) {               // 16 gathers in flight
        unsigned uv[16];
#pragma unroll
        for (int q = 0; q < 16; ++q) {
            int c = col[j + q];                    // uniform addr -> s_load
            uv[q] = HS2[(size_t)c * 64 + lane];    // saddr gather, 256B/wave
        }
#pragma unroll
        for (int q = 0; q < 16; ++q) {
            float f0, f1; bf2_unpack(uv[q], f0, f1);
            acc.x += f0; acc.y += f1;
        }
    }
    while (j < end) {                              // uniform masked tail, 8-deep
        unsigned uv[8];
#pragma unroll
        for (int q = 0; q < 8; ++q) {
            int jq = j + q;
            int c = (jq < end) ? col[jq] : node;   // uniform select, safe row
            uv[q] = HS2[(size_t)c * 64 + lane];
        }
#pragma unroll
        for (int q = 0; q < 8; ++q) {
            unsigned u = (j + q < end) ? uv[q] : 0u;   // zero -> adds +0.0f
            float f0, f1; bf2_unpack(u, f0, f1);
            acc.x += f0; acc.y += f1;
        }
        j += 8;
    }
    float s = dinv[node];
    float2 b = *(const float2*)&bias[2 * lane];
    float2 o;
    o.x = fmaxf(acc.x * s + b.x, 0.f);
    o.y = fmaxf(acc.y * s + b.y, 0.f);
    *(float2*)&Y[(long)node * HID + 2 * lane] = o;
}

// ---------------- fused layer-2 aggregation + relu + head (R6 exact) ----------------
__global__ __launch_bounds__(256) void agg_relu_head(const unsigned* __restrict__ HS2,
                                                     const int* __restrict__ rowptr,
                                                     const int* __restrict__ col,
                                                     const float* __restrict__ dinv,
                                                     const float* __restrict__ bias,
                                                     const float* __restrict__ Wl,
                                                     const float* __restrict__ bl,
                                                     float* __restrict__ out, int n) {
    int lane = threadIdx.x & 63;
    int node = __builtin_amdgcn_readfirstlane(blockIdx.x * 4 + (threadIdx.x >> 6));
    if (node >= n) return;
    int start = __builtin_amdgcn_readfirstlane(rowptr[node]);
    int end   = __builtin_amdgcn_readfirstlane(rowptr[node + 1]);
    float2 acc;
    {
        float f0, f1;
        bf2_unpack(HS2[(size_t)node * 64 + lane], f0, f1);   // self loop
        acc.x = f0; acc.y = f1;
    }
    int j = start;
    for (; j + 16 <= end; j += 16) {
        unsigned uv[16];
#pragma unroll
        for (int q = 0; q < 16; ++q) {
            int c = col[j + q];                    // uniform addr -> s_load
            uv[q] = HS2[(size_t)c * 64 + lane];
        }
#pragma unroll
        for (int q = 0; q < 16; ++q) {
            float f0, f1; bf2_unpack(uv[q], f0, f1);
            acc.x += f0; acc.y += f1;
        }
    }
    while (j < end) {
        unsigned uv[8];
#pragma unroll
        for (int q = 0; q < 8; ++q) {
            int jq = j + q;
            int c = (jq < end) ? col[jq] : node;
            uv[q] = HS2[(size_t)c * 64 + lane];
        }
#pragma unroll
        for (int q = 0; q < 8; ++q) {
            unsigned u = (j + q < end) ? uv[q] : 0u;
            float f0, f1; bf2_unpack(u, f0, f1);
            acc.x += f0; acc.y += f1;
        }
        j += 8;
    }
    float s = dinv[node];
    float2 b = *(const float2*)&bias[2 * lane];
    float vx = fmaxf(acc.x * s + b.x, 0.f);   // feature 2*lane
    float vy = fmaxf(acc.y * s + b.y, 0.f);   // feature 2*lane+1
    float4 wl = *(const float4*)&Wl[4 * lane];
    float a0 = vx * wl.x + vy * wl.z;
    float a1 = vx * wl.y + vy * wl.w;
#pragma unroll
    for (int off = 32; off > 0; off >>= 1) {
        a0 += __shfl_xor(a0, off);
        a1 += __shfl_xor(a1, off);
    }
    if (lane == 0) {
        out[(long)node * 2 + 0] = a0 + bl[0];
        out[(long)node * 2 + 1] = a1 + bl[1];
    }
}

// ---------------- launch ----------------
extern "C" void kernel_launch(void* const* d_in, const int* in_sizes, int n_in,
                              void* d_out, int out_size, void* d_ws, size_t ws_size,
                              hipStream_t stream) {
    const float* x  = (const float*)d_in[0];
    const int*   ei = (const int*)d_in[1];
    const float* W1 = (const float*)d_in[2];
    const float* b1 = (const float*)d_in[3];
    const float* W2 = (const float*)d_in[4];
    const float* b2 = (const float*)d_in[5];
    const float* Wl = (const float*)d_in[6];
    const float* bl = (const float*)d_in[7];
    float* out = (float*)d_out;

    int n = in_sizes[0] / FIN;          // 200000
    int E = in_sizes[1] / 2;            // 3200000
    int NB = (n + NPB - 1) / NPB;       // 782 buckets
    int ntiles = n / 64;                // 3125 row tiles
    const int* srcp = ei;
    const int* dstp = ei + E;

    char* w = (char*)d_ws;
    auto alloc = [&](size_t bytes) {
        char* p = w;
        w += (bytes + 255) & ~(size_t)255;
        return (void*)p;
    };
    int*      gcur    = (int*)     alloc((size_t)NB * 16 * 4);   // 64B-padded cursors
    int*      bb      = (int*)     alloc(((size_t)NB + 1) * 4);
    int*      rowptr  = (int*)     alloc(((size_t)n + 1) * 4);
    float*    dinv    = (float*)   alloc((size_t)n * 4);
    int*      colv    = (int*)     alloc((size_t)E * 4);
    unsigned* hbuf    = (unsigned*)alloc((size_t)n * 64 * 4);    // bf16-packed HS (51 MB)
    float*    ybuf    = (float*)   alloc((size_t)n * HID * 4);
    short8*   w1sw    = (short8*)  alloc((size_t)2 * K32C1 * 8 * 64 * 16);
    short8*   w2sw    = (short8*)  alloc((size_t)2 * K32C2 * 8 * 64 * 16);
    // bucketed packed words (14.4 MB) alias ybuf (102 MB): ybuf dead until agg_relu
    // writes it, and bucketed is dead after build_csr (which precedes agg_relu).
    unsigned* bucketed = (unsigned*)ybuf;

    hipMemsetAsync(gcur, 0, (size_t)NB * 16 * 4, stream);

    // W pre-swizzle (one tiny launch for both weights)
    wswz_both<<<20, 256, 0, stream>>>(W1, w1sw, W2, w2sw);

    // bucketed CSR build (separate launches -> launch-boundary coherence, no fences)
    bucket_scatter<<<(E + EPB - 1) / EPB, 256, 0, stream>>>(srcp, dstp, gcur,
                                                            bucketed, E, n, NB);
    bucket_scan<<<1, 256, 0, stream>>>(gcur, bb, NB, rowptr, n);
    build_csr<<<NB, 256, 0, stream>>>(bucketed, bb, dinv, rowptr, colv, n);

    // layer 1 GEMM: W1-hi staged in LDS (48KB, 3 blocks/CU), W1-lo from L2
    gemm_lds<K32C1, false><<<768, 256, 0, stream>>>(x, w1sw, dinv, hbuf,
                                                    FIN, FIN / 32, ntiles);
    // layer 1 aggregation
    agg_relu<<<(n + 3) / 4, 256, 0, stream>>>(hbuf, rowptr, colv, dinv, b1, ybuf, n);

    // layer 2 GEMM: full W2 hi+lo staged in LDS (64KB, 2 blocks/CU)
    gemm_lds<K32C2, true><<<512, 256, 0, stream>>>(ybuf, w2sw, dinv, hbuf,
                                                   HID, HID / 32, ntiles);

    // fused layer-2 aggregation + relu + head
    agg_relu_head<<<(n + 3) / 4, 256, 0, stream>>>(hbuf, rowptr, colv, dinv, b2,
                                                   Wl, bl, out, n);
}